// Round 5
// baseline (129.754 us; speedup 1.0000x reference)
//
#include <hip/hip_runtime.h>
#include <math.h>

#define EPS  1e-6f
#define DD   256
#define NSUP 5
#define NQ   8
#define SEQ  13
#define L2E  1.44269504088896f
#define LN2  0.693147180559945f
#define NEP  2048            // episodes
#define NROW 16384           // NEP*NQ query rows
#define NCOL 2048            // anchor columns

typedef short bf16x8 __attribute__((ext_vector_type(8)));
typedef unsigned short u16x4 __attribute__((ext_vector_type(4)));
typedef float f32x4  __attribute__((ext_vector_type(4)));

__device__ __forceinline__ ushort f2bf(float f) {
  union { float f; unsigned u; } v; v.f = f;
  unsigned r = v.u + 0x7FFFu + ((v.u >> 16) & 1u);   // round-to-nearest-even
  return (ushort)(r >> 16);
}
__device__ __forceinline__ float bf2f(short u) {
  union { unsigned u; float f; } v; v.u = ((unsigned)(unsigned short)u) << 16;
  return v.f;
}

// ---------------------------------------------------------------------------
// prep (r8-proven, unchanged): anchors/queries in MFMA-fragment-SWIZZLED order;
// element (c,d) -> ushort idx (((c>>4)*8+(d>>5))*64 + ((d>>3)&3)*16 + (c&15))*8+(d&7).
// cb[c] = -log2(e)*(sum(a^2) - 2*eps*sum(a)); row-constant cq cancels.
// ---------------------------------------------------------------------------
__global__ __launch_bounds__(256) void proto_prep(
    const float* __restrict__ x, float* __restrict__ cb,
    ushort* __restrict__ Asw, ushort* __restrict__ Qsw,
    float* __restrict__ accum, int* __restrict__ fincount) {
  const int tid = threadIdx.x, g = tid >> 6, l = tid & 63;
  const int n = blockIdx.x * 4 + g;
  if (blockIdx.x == 0 && tid == 0) { accum[0] = 0.f; accum[1] = 0.f; fincount[0] = 0; }

  const float4* xr4 = (const float4*)(x + (size_t)n * SEQ * DD);

  const int d0   = l * 4;
  const int kk   = d0 >> 5, quad = (d0 >> 3) & 3, j = d0 & 7;   // j in {0,4}
  const size_t chunk_d = (size_t)kk * 64 + (size_t)quad * 16;

  float4 a = {0.f, 0.f, 0.f, 0.f};
  #pragma unroll
  for (int s = 0; s < NSUP; ++s) {
    float4 v = xr4[s * 64 + l];
    a.x += v.x; a.y += v.y; a.z += v.z; a.w += v.w;
  }
  a.x *= 0.2f; a.y *= 0.2f; a.z *= 0.2f; a.w *= 0.2f;
  {
    const size_t idx = (((size_t)(n >> 4) * 8) * 64 + chunk_d + (n & 15)) * 8 + j;
    u16x4 o = {f2bf(a.x), f2bf(a.y), f2bf(a.z), f2bf(a.w)};
    *(u16x4*)(Asw + idx) = o;
  }
  float s1 = a.x + a.y + a.z + a.w;
  float s2 = a.x * a.x + a.y * a.y + a.z * a.z + a.w * a.w;
  #pragma unroll
  for (int off = 32; off; off >>= 1) {
    s1 += __shfl_xor(s1, off);
    s2 += __shfl_xor(s2, off);
  }
  if (l == 0) cb[n] = -L2E * (s2 - 2.f * EPS * s1);

  #pragma unroll
  for (int s = 0; s < NQ; ++s) {
    float4 q = xr4[(NSUP + s) * 64 + l];
    const int row = n * NQ + s;
    const size_t idx = (((size_t)(row >> 4) * 8) * 64 + chunk_d + (row & 15)) * 8 + j;
    u16x4 o = {f2bf(q.x), f2bf(q.y), f2bf(q.z), f2bf(q.w)};
    *(u16x4*)(Qsw + idx) = o;
  }
}

// ---------------------------------------------------------------------------
// main r17: T3/T4 sync-structure test. r13-r16 eliminated spill/occupancy/
// LDS-volume/step-count as the wall: 4 structures all 48-53 us with ~50%
// issue-idle. The shared invariant is the full-drain barrier (__syncthreads
// = s_waitcnt vmcnt(0) lgkmcnt(0) + s_barrier): every staging load drained
// before any wave proceeds (m97-structure plateau; m218 isolated counted-
// vmcnt vs drain-0 = +38-73%). This round keeps r15's thin-wave LDS-staged
// shape and changes ONLY the sync: 3-deep LDS buffers, raw s_barrier, and
// counted s_waitcnt vmcnt(2) — each wave stages 2 chunks/step; at the wait,
// the <=2 outstanding are the NEWEST (FIFO), so tile t is guaranteed landed
// while t+1/t+2 loads stay in flight across the barrier.
//   loop t: vmcnt(2); s_barrier; stage(t+2 -> buf[(t+2)%3]); compute(t).
// stage(t+2) overwrites buf[(t-1)%3] strictly AFTER the barrier, i.e. after
// all waves finished compute(t-1): race-free. Uniform dummy clamp-stage at
// the tail keeps the FIFO count exact. Slot update / merge order / label
// pass numerically IDENTICAL to r15 -> absmax 0 preserved.
// 16 waves = 4 rowg x 4 colg; wave = 16 rows (af[8]=32 VGPR) x 512-col
// stripe (32 tiles). LDS: 4 groups x 3 bufs x 8 KB = 96 KB + merge ~4 KB.
// MFMA layouts (verified): A m=lane&15,k=quad*8+j ; B n=lane&15,k=quad*8+j ;
// C col=lane&15,row=quad*4+reg.
// ---------------------------------------------------------------------------
__global__ __launch_bounds__(1024, 4) void proto_main(
    const ushort* __restrict__ Qsw, const ushort* __restrict__ Asw,
    const float* __restrict__ cb, const int* __restrict__ label,
    float* __restrict__ accum, int* __restrict__ fincount,
    float* __restrict__ out) {
  const int tid  = threadIdx.x;
  const int wid  = tid >> 6, lane = tid & 63;
  const int quad = lane >> 4, lcol = lane & 15;
  const int rowg = wid & 3, colg = wid >> 2;        // 4 x 4 wave grid
  const int r0   = blockIdx.x * 64;

  const bf16x8* qb = (const bf16x8*)Qsw;
  const bf16x8* bb = (const bf16x8*)Asw;

  __shared__ bf16x8 Bl[4][3][8][64];                 // 96 KiB, 3-deep staging

  // resident A fragments: this wave's 16 rows x 8 K-chunks (32 VGPR)
  bf16x8 af[8];
  {
    const size_t base = ((size_t)(blockIdx.x * 4 + rowg) * 8) * 64 + lane;
    #pragma unroll
    for (int kk = 0; kk < 8; ++kk) af[kk] = qb[base + (size_t)kk * 64];
  }

  float m[4], s[4];
  int   bi[4];
  #pragma unroll
  for (int i = 0; i < 4; ++i) { m[i] = -1e30f; s[i] = 0.f; bi[i] = 0x7fffffff; }

  // wave (rowg) stages K-chunks {2*rowg, 2*rowg+1}: 2 x global_load_lds
  // width=16 per tile-step (linear dest: base + lane*16). [G13/T3]
  const int kk0 = rowg * 2;
  auto stage = [&](int tl, int b) {
    const int T = colg * 32 + (tl < 32 ? tl : 31);   // clamped dummy at tail
    #pragma unroll
    for (int k2 = 0; k2 < 2; ++k2) {
      const int kk = kk0 + k2;
      const ushort* src = Asw + (((size_t)T * 8 + kk) * 64 + lane) * 8;
      __builtin_amdgcn_global_load_lds(
          (const __attribute__((address_space(1))) void*)src,
          (__attribute__((address_space(3))) void*)&Bl[colg][b][kk][0],
          16, 0, 0);
    }
  };

  auto compute = [&](int tl, int b) {
    f32x4 c = {0.f, 0.f, 0.f, 0.f};
    #pragma unroll
    for (int kk = 0; kk < 8; ++kk)
      c = __builtin_amdgcn_mfma_f32_16x16x32_bf16(af[kk], Bl[colg][b][kk][lane],
                                                  c, 0, 0, 0);
    const int   colIdx = (colg * 32 + tl) * 16 + lcol;
    const float cbv    = cb[colIdx];                 // 64-B broadcast, L2-hot
    #pragma unroll
    for (int i = 0; i < 4; ++i) {
      float v2 = fmaf(c[i], 2.f * L2E, cbv);         // log2-frame shifted logit
      float dv = v2 - m[i];
      bool  gt = dv > 0.f;
      float e  = exp2f(-fabsf(dv));                  // single non-unit exp factor
      s[i]  = fmaf(s[i], gt ? e : 1.f, gt ? 1.f : e);
      m[i]  = fmaxf(m[i], v2);
      bi[i] = gt ? colIdx : bi[i];                   // strict >: first max wins
    }
  };

  stage(0, 0);
  stage(1, 1);

  #pragma unroll 1
  for (int t = 0; t < 32; ++t) {
    // counted wait: <=2 outstanding = the newest stage (FIFO) -> tile t landed;
    // raw barrier publishes WITHOUT draining the in-flight staging loads. [T4]
    asm volatile("s_waitcnt vmcnt(2)" ::: "memory");
    asm volatile("s_barrier" ::: "memory");
    stage(t + 2, (t + 2) % 3);                       // overwrites buf[(t-1)%3]
    __builtin_amdgcn_s_setprio(1);
    compute(t, t % 3);
    __builtin_amdgcn_s_setprio(0);
  }

  // merge across the 16 lanes sharing rows (cols differ)
  #pragma unroll
  for (int mask = 1; mask < 16; mask <<= 1) {
    #pragma unroll
    for (int i = 0; i < 4; ++i) {
      float om = __shfl_xor(m[i], mask);
      float os = __shfl_xor(s[i], mask);
      int   oi = __shfl_xor(bi[i], mask);
      float nm = fmaxf(m[i], om);
      s[i] = s[i] * exp2f(m[i] - nm) + os * exp2f(om - nm);
      bool better = (om > m[i]) || (om == m[i] && oi < bi[i]);
      bi[i] = better ? oi : bi[i];
      m[i]  = nm;
    }
  }

  __shared__ float sm[4][64], ssh[4][64], slab[64];
  __shared__ int   sbi[4][64];
  if (lcol == 0) {
    #pragma unroll
    for (int i = 0; i < 4; ++i) {
      int rl = rowg * 16 + quad * 4 + i;
      sm[colg][rl] = m[i]; ssh[colg][rl] = s[i]; sbi[colg][rl] = bi[i];
    }
  }

  // label-logit post-pass (r11-proven): 8 lanes per row, 64 rows -> tids 0..511
  // (whole waves 0..7: shuffles stay wave-uniform); bf16 dot with the same
  // rounding as the MFMA path.
  if (tid < 512) {
    const int rl = tid >> 3, l = tid & 7;
    const int row = r0 + rl;
    const int lab = label[row >> 3];
    const int kk  = l;
    float dot = 0.f;
    const size_t qc = ((size_t)(row >> 4) * 8 + kk) * 64 + (row & 15);
    const size_t ac = ((size_t)(lab >> 4) * 8 + kk) * 64 + (lab & 15);
    #pragma unroll
    for (int qd = 0; qd < 4; ++qd) {
      bf16x8 qv = qb[qc + qd * 16];
      bf16x8 av = bb[ac + qd * 16];
      #pragma unroll
      for (int j = 0; j < 8; ++j) dot = fmaf(bf2f(qv[j]), bf2f(av[j]), dot);
    }
    dot += __shfl_xor(dot, 1);
    dot += __shfl_xor(dot, 2);
    dot += __shfl_xor(dot, 4);
    if (l == 0) slab[rl] = fmaf(dot, 2.f * L2E, cb[lab]);  // shifted label logit
  }
  __syncthreads();

  if (tid < 64) {                                  // one full wave
    float mm = sm[0][tid], sv = ssh[0][tid];
    int   b  = sbi[0][tid];
    #pragma unroll
    for (int w = 1; w < 4; ++w) {                  // stripes in ascending col order
      float om = sm[w][tid], os = ssh[w][tid];
      int   oi = sbi[w][tid];
      float nm = fmaxf(mm, om);
      sv = sv * exp2f(mm - nm) + os * exp2f(om - nm);
      bool better = (om > mm) || (om == mm && oi < b);
      b = better ? oi : b;
      mm = nm;
    }
    const int row = r0 + tid;
    const int lb  = label[row >> 3];
    float loss = LN2 * (mm + log2f(sv) - slab[tid]);
    float corr = (b == lb) ? 1.f : 0.f;
    #pragma unroll
    for (int mask = 32; mask; mask >>= 1) {        // full-wave xor reduce
      loss += __shfl_xor(loss, mask);
      corr += __shfl_xor(corr, mask);
    }
    if (tid == 0) {
      atomicAdd(&accum[0], loss);
      atomicAdd(&accum[1], corr);
      __threadfence();
      if (atomicAdd(fincount, 1) == (int)gridDim.x - 1) {
        out[0] = atomicAdd(&accum[0], 0.f) / (float)NROW;   // coherent reads
        out[1] = atomicAdd(&accum[1], 0.f) * 100.f / (float)NROW;
      }
    }
  }
}

// ---------------------------------------------------------------------------
extern "C" void kernel_launch(void* const* d_in, const int* in_sizes, int n_in,
                              void* d_out, int out_size, void* d_ws, size_t ws_size,
                              hipStream_t stream) {
  const float* x     = (const float*)d_in[0];
  const int*   label = (const int*)d_in[1];
  float* out = (float*)d_out;

  // ws layout (float-sized slots): [0:2) accum | [2] fincount |
  // [16,16+NCOL) cb | Asw (NCOL*DD ushort) | Qsw (NROW*DD ushort)
  float*  W        = (float*)d_ws;
  float*  accum    = W;
  int*    fincount = (int*)(W + 2);
  float*  cb       = W + 16;
  ushort* Asw      = (ushort*)(cb + NCOL);
  ushort* Qsw      = Asw + (size_t)NCOL * DD;

  hipLaunchKernelGGL(proto_prep, dim3(NEP / 4), dim3(256), 0, stream,
                     x, cb, Asw, Qsw, accum, fincount);
  hipLaunchKernelGGL(proto_main, dim3(NROW / 64), dim3(1024), 0, stream,
                     Qsw, Asw, cb, label, accum, fincount, out);
}

// Round 6
// 126.679 us; speedup vs baseline: 1.0243x; 1.0243x over previous
//
#include <hip/hip_runtime.h>
#include <math.h>

#define EPS  1e-6f
#define DD   256
#define NSUP 5
#define NQ   8
#define SEQ  13
#define L2E  1.44269504088896f
#define LN2  0.693147180559945f
#define NEP  2048            // episodes
#define NROW 16384           // NEP*NQ query rows
#define NCOL 2048            // anchor columns

typedef short bf16x8 __attribute__((ext_vector_type(8)));
typedef unsigned short u16x4 __attribute__((ext_vector_type(4)));
typedef float f32x4  __attribute__((ext_vector_type(4)));

__device__ __forceinline__ ushort f2bf(float f) {
  union { float f; unsigned u; } v; v.f = f;
  unsigned r = v.u + 0x7FFFu + ((v.u >> 16) & 1u);   // round-to-nearest-even
  return (ushort)(r >> 16);
}
__device__ __forceinline__ float bf2f(short u) {
  union { unsigned u; float f; } v; v.u = ((unsigned)(unsigned short)u) << 16;
  return v.f;
}

// ---------------------------------------------------------------------------
// prep (r8-proven, unchanged): anchors/queries in MFMA-fragment-SWIZZLED order;
// element (c,d) -> ushort idx (((c>>4)*8+(d>>5))*64 + ((d>>3)&3)*16 + (c&15))*8+(d&7).
// cb[c] = -log2(e)*(sum(a^2) - 2*eps*sum(a)); row-constant cq cancels.
// ---------------------------------------------------------------------------
__global__ __launch_bounds__(256) void proto_prep(
    const float* __restrict__ x, float* __restrict__ cb,
    ushort* __restrict__ Asw, ushort* __restrict__ Qsw,
    float* __restrict__ accum, int* __restrict__ fincount) {
  const int tid = threadIdx.x, g = tid >> 6, l = tid & 63;
  const int n = blockIdx.x * 4 + g;
  if (blockIdx.x == 0 && tid == 0) { accum[0] = 0.f; accum[1] = 0.f; fincount[0] = 0; }

  const float4* xr4 = (const float4*)(x + (size_t)n * SEQ * DD);

  const int d0   = l * 4;
  const int kk   = d0 >> 5, quad = (d0 >> 3) & 3, j = d0 & 7;   // j in {0,4}
  const size_t chunk_d = (size_t)kk * 64 + (size_t)quad * 16;

  float4 a = {0.f, 0.f, 0.f, 0.f};
  #pragma unroll
  for (int s = 0; s < NSUP; ++s) {
    float4 v = xr4[s * 64 + l];
    a.x += v.x; a.y += v.y; a.z += v.z; a.w += v.w;
  }
  a.x *= 0.2f; a.y *= 0.2f; a.z *= 0.2f; a.w *= 0.2f;
  {
    const size_t idx = (((size_t)(n >> 4) * 8) * 64 + chunk_d + (n & 15)) * 8 + j;
    u16x4 o = {f2bf(a.x), f2bf(a.y), f2bf(a.z), f2bf(a.w)};
    *(u16x4*)(Asw + idx) = o;
  }
  float s1 = a.x + a.y + a.z + a.w;
  float s2 = a.x * a.x + a.y * a.y + a.z * a.z + a.w * a.w;
  #pragma unroll
  for (int off = 32; off; off >>= 1) {
    s1 += __shfl_xor(s1, off);
    s2 += __shfl_xor(s2, off);
  }
  if (l == 0) cb[n] = -L2E * (s2 - 2.f * EPS * s1);

  #pragma unroll
  for (int s = 0; s < NQ; ++s) {
    float4 q = xr4[(NSUP + s) * 64 + l];
    const int row = n * NQ + s;
    const size_t idx = (((size_t)(row >> 4) * 8) * 64 + chunk_d + (row & 15)) * 8 + j;
    u16x4 o = {f2bf(q.x), f2bf(q.y), f2bf(q.z), f2bf(q.w)};
    *(u16x4*)(Qsw + idx) = o;
  }
}

// ---------------------------------------------------------------------------
// main r18: poison removal. Diagnosis across r12-r17: every structure kept a
// per-tile GLOBAL load cb[colIdx] feeding softmax; the compiler's vmcnt wait
// for that value (conservative with global_load_lds interleaved in the VMEM
// queue) drained ALL staging prefetch inside every tile interval — this one
// dependency explains the 48-53 us plateau across 5 structures, and why r17's
// hand vmcnt(2) did nothing (subsumed by the compiler's wait).
// Changes vs r16 (same 2 rowg x 8 colg, 2-buf, __syncthreads shape):
//  (1) cb staged to LDS (sCb[2048], 8 KB) at block start; per-tile cbv is a
//      conflict-free broadcast ds_read -> ZERO global loads in the main loop.
//  (2) T15-style skew: softmax(t-1) executes during tile t's interval,
//      interleaved with MFMA(t) (independent chains; static cE/cO 2-state,
//      rule #20). MFMA and VALU overlap within each wave.
// Slot-update order per row is unchanged (ascending tiles per stripe) ->
// bit-identical output. LDS 128K(Bl) + 8K(sCb) + 6.5K(merge) = 142.5 KB.
// VGPR ~80 < 128 cap of (1024,4): no spill.
// MFMA layouts (verified): A m=lane&15,k=quad*8+j ; B n=lane&15,k=quad*8+j ;
// C col=lane&15,row=quad*4+reg.
// ---------------------------------------------------------------------------
__global__ __launch_bounds__(1024, 4) void proto_main(
    const ushort* __restrict__ Qsw, const ushort* __restrict__ Asw,
    const float* __restrict__ cb, const int* __restrict__ label,
    float* __restrict__ accum, int* __restrict__ fincount,
    float* __restrict__ out) {
  const int tid  = threadIdx.x;
  const int wid  = tid >> 6, lane = tid & 63;
  const int quad = lane >> 4, lcol = lane & 15;
  const int rowg = wid & 1, colg = wid >> 1;        // 2 x 8 wave grid
  const int r0   = blockIdx.x * 64;

  const bf16x8* qb = (const bf16x8*)Qsw;
  const bf16x8* bb = (const bf16x8*)Asw;

  __shared__ bf16x8 Bl[8][2][8][64];                 // 128 KiB B staging
  __shared__ float  sCb[NCOL];                       // 8 KiB col-constant table

  // one-time cb -> LDS (coalesced; ready after first __syncthreads)
  sCb[tid]        = cb[tid];
  sCb[tid + 1024] = cb[tid + 1024];

  // resident A fragments: this wave's 32 rows (2 sets) x 8 K-chunks (64 VGPR)
  bf16x8 af[2][8];
  #pragma unroll
  for (int set = 0; set < 2; ++set) {
    const size_t base = ((size_t)(blockIdx.x * 4 + rowg * 2 + set) * 8) * 64 + lane;
    #pragma unroll
    for (int kk = 0; kk < 8; ++kk) af[set][kk] = qb[base + (size_t)kk * 64];
  }

  float m[2][4], s[2][4];
  int   bi[2][4];
  #pragma unroll
  for (int set = 0; set < 2; ++set)
    #pragma unroll
    for (int i = 0; i < 4; ++i) {
      m[set][i] = -1e30f; s[set][i] = 0.f; bi[set][i] = 0x7fffffff;
    }

  // wave (rowg) stages K-chunks 4*rowg..4*rowg+3 of tile tl into buf b:
  // 4 x global_load_lds width=16 (linear dest: base + lane*16). [G13/T3]
  const int kk0 = rowg * 4;
  auto stage = [&](int tl, int b) {
    const int T = colg * 16 + tl;
    #pragma unroll
    for (int k2 = 0; k2 < 4; ++k2) {
      const int kk = kk0 + k2;
      const ushort* src = Asw + (((size_t)T * 8 + kk) * 64 + lane) * 8;
      __builtin_amdgcn_global_load_lds(
          (const __attribute__((address_space(1))) void*)src,
          (__attribute__((address_space(3))) void*)&Bl[colg][b][kk][0],
          16, 0, 0);
    }
  };

  auto mfmaT = [&](int tl, f32x4 (&c)[2]) {
    c[0] = f32x4{0.f, 0.f, 0.f, 0.f};
    c[1] = f32x4{0.f, 0.f, 0.f, 0.f};
    const int b = tl & 1;
    #pragma unroll
    for (int kk = 0; kk < 8; ++kk) {
      bf16x8 bf = Bl[colg][b][kk][lane];
      c[0] = __builtin_amdgcn_mfma_f32_16x16x32_bf16(af[0][kk], bf, c[0], 0, 0, 0);
      c[1] = __builtin_amdgcn_mfma_f32_16x16x32_bf16(af[1][kk], bf, c[1], 0, 0, 0);
    }
  };

  auto smax = [&](int tl, f32x4 (&c)[2]) {
    const int   colIdx = (colg * 16 + tl) * 16 + lcol;
    const float cbv    = sCb[colIdx];                // LDS broadcast, no vmcnt
    #pragma unroll
    for (int set = 0; set < 2; ++set) {
      #pragma unroll
      for (int i = 0; i < 4; ++i) {
        float v2 = fmaf(c[set][i], 2.f * L2E, cbv);  // log2-frame shifted logit
        float dv = v2 - m[set][i];
        bool  gt = dv > 0.f;
        float e  = exp2f(-fabsf(dv));                // single non-unit exp factor
        s[set][i]  = fmaf(s[set][i], gt ? e : 1.f, gt ? 1.f : e);
        m[set][i]  = fmaxf(m[set][i], v2);
        bi[set][i] = gt ? colIdx : bi[set][i];       // strict >: first max wins
      }
    }
  };

  f32x4 cE[2], cO[2];                                // static 2-state (rule #20)

  stage(0, 0);
  __syncthreads();                                   // b0 + sCb ready
  stage(1, 1);
  mfmaT(0, cE);
  __syncthreads();                                   // b1 ready; b0 reads done

  #pragma unroll 1
  for (int t = 1; t < 15; t += 2) {
    stage(t + 1, 0);                                 // even tile -> b0
    mfmaT(t, cO);                                    // odd tile from b1
    smax(t - 1, cE);                                 // skewed softmax (indep)
    __syncthreads();
    stage(t + 2, 1);                                 // odd tile -> b1
    mfmaT(t + 1, cE);                                // even tile from b0
    smax(t, cO);
    __syncthreads();
  }
  mfmaT(15, cO);                                     // b1 staged at t=13 half 2
  smax(14, cE);
  smax(15, cO);

  // merge across the 16 lanes sharing rows (cols differ)
  #pragma unroll
  for (int mask = 1; mask < 16; mask <<= 1) {
    #pragma unroll
    for (int set = 0; set < 2; ++set)
      #pragma unroll
      for (int i = 0; i < 4; ++i) {
        float om = __shfl_xor(m[set][i], mask);
        float os = __shfl_xor(s[set][i], mask);
        int   oi = __shfl_xor(bi[set][i], mask);
        float nm = fmaxf(m[set][i], om);
        s[set][i] = s[set][i] * exp2f(m[set][i] - nm) + os * exp2f(om - nm);
        bool better = (om > m[set][i]) || (om == m[set][i] && oi < bi[set][i]);
        bi[set][i] = better ? oi : bi[set][i];
        m[set][i]  = nm;
      }
  }

  __shared__ float sm[8][64], ssh[8][64], slab[64];
  __shared__ int   sbi[8][64];
  if (lcol == 0) {
    #pragma unroll
    for (int set = 0; set < 2; ++set)
      #pragma unroll
      for (int i = 0; i < 4; ++i) {
        int rl = rowg * 32 + set * 16 + quad * 4 + i;
        sm[colg][rl] = m[set][i]; ssh[colg][rl] = s[set][i]; sbi[colg][rl] = bi[set][i];
      }
  }

  // label-logit post-pass (r11-proven): 8 lanes per row, 64 rows -> tids 0..511
  // (whole waves 0..7: shuffles stay wave-uniform); bf16 dot with the same
  // rounding as the MFMA path.
  if (tid < 512) {
    const int rl = tid >> 3, l = tid & 7;
    const int row = r0 + rl;
    const int lab = label[row >> 3];
    const int kk  = l;
    float dot = 0.f;
    const size_t qc = ((size_t)(row >> 4) * 8 + kk) * 64 + (row & 15);
    const size_t ac = ((size_t)(lab >> 4) * 8 + kk) * 64 + (lab & 15);
    #pragma unroll
    for (int qd = 0; qd < 4; ++qd) {
      bf16x8 qv = qb[qc + qd * 16];
      bf16x8 av = bb[ac + qd * 16];
      #pragma unroll
      for (int j = 0; j < 8; ++j) dot = fmaf(bf2f(qv[j]), bf2f(av[j]), dot);
    }
    dot += __shfl_xor(dot, 1);
    dot += __shfl_xor(dot, 2);
    dot += __shfl_xor(dot, 4);
    if (l == 0) slab[rl] = fmaf(dot, 2.f * L2E, sCb[lab]);  // shifted label logit
  }
  __syncthreads();

  if (tid < 64) {                                  // one full wave
    float mm = sm[0][tid], sv = ssh[0][tid];
    int   b  = sbi[0][tid];
    #pragma unroll
    for (int w = 1; w < 8; ++w) {                  // stripes in ascending col order
      float om = sm[w][tid], os = ssh[w][tid];
      int   oi = sbi[w][tid];
      float nm = fmaxf(mm, om);
      sv = sv * exp2f(mm - nm) + os * exp2f(om - nm);
      bool better = (om > mm) || (om == mm && oi < b);
      b = better ? oi : b;
      mm = nm;
    }
    const int row = r0 + tid;
    const int lb  = label[row >> 3];
    float loss = LN2 * (mm + log2f(sv) - slab[tid]);
    float corr = (b == lb) ? 1.f : 0.f;
    #pragma unroll
    for (int mask = 32; mask; mask >>= 1) {        // full-wave xor reduce
      loss += __shfl_xor(loss, mask);
      corr += __shfl_xor(corr, mask);
    }
    if (tid == 0) {
      atomicAdd(&accum[0], loss);
      atomicAdd(&accum[1], corr);
      __threadfence();
      if (atomicAdd(fincount, 1) == (int)gridDim.x - 1) {
        out[0] = atomicAdd(&accum[0], 0.f) / (float)NROW;   // coherent reads
        out[1] = atomicAdd(&accum[1], 0.f) * 100.f / (float)NROW;
      }
    }
  }
}

// ---------------------------------------------------------------------------
extern "C" void kernel_launch(void* const* d_in, const int* in_sizes, int n_in,
                              void* d_out, int out_size, void* d_ws, size_t ws_size,
                              hipStream_t stream) {
  const float* x     = (const float*)d_in[0];
  const int*   label = (const int*)d_in[1];
  float* out = (float*)d_out;

  // ws layout (float-sized slots): [0:2) accum | [2] fincount |
  // [16,16+NCOL) cb | Asw (NCOL*DD ushort) | Qsw (NROW*DD ushort)
  float*  W        = (float*)d_ws;
  float*  accum    = W;
  int*    fincount = (int*)(W + 2);
  float*  cb       = W + 16;
  ushort* Asw      = (ushort*)(cb + NCOL);
  ushort* Qsw      = Asw + (size_t)NCOL * DD;

  hipLaunchKernelGGL(proto_prep, dim3(NEP / 4), dim3(256), 0, stream,
                     x, cb, Asw, Qsw, accum, fincount);
  hipLaunchKernelGGL(proto_main, dim3(NROW / 64), dim3(1024), 0, stream,
                     Qsw, Asw, cb, label, accum, fincount, out);
}

// Round 7
// 121.742 us; speedup vs baseline: 1.0658x; 1.0406x over previous
//
#include <hip/hip_runtime.h>
#include <math.h>

#define EPS  1e-6f
#define DD   256
#define NSUP 5
#define NQ   8
#define SEQ  13
#define L2E  1.44269504088896f
#define LN2  0.693147180559945f
#define NEP  2048            // episodes
#define NROW 16384           // NEP*NQ query rows
#define NCOL 2048            // anchor columns

typedef short bf16x8 __attribute__((ext_vector_type(8)));
typedef unsigned short u16x4 __attribute__((ext_vector_type(4)));
typedef float f32x4  __attribute__((ext_vector_type(4)));

__device__ __forceinline__ ushort f2bf(float f) {
  union { float f; unsigned u; } v; v.f = f;
  unsigned r = v.u + 0x7FFFu + ((v.u >> 16) & 1u);   // round-to-nearest-even
  return (ushort)(r >> 16);
}
__device__ __forceinline__ float bf2f(short u) {
  union { unsigned u; float f; } v; v.u = ((unsigned)(unsigned short)u) << 16;
  return v.f;
}

// ---------------------------------------------------------------------------
// prep (r8-proven, unchanged): anchors/queries in MFMA-fragment-SWIZZLED order;
// element (c,d) -> ushort idx (((c>>4)*8+(d>>5))*64 + ((d>>3)&3)*16 + (c&15))*8+(d&7).
// cb[c] = -log2(e)*(sum(a^2) - 2*eps*sum(a)); row-constant cq cancels.
// ---------------------------------------------------------------------------
__global__ __launch_bounds__(256) void proto_prep(
    const float* __restrict__ x, float* __restrict__ cb,
    ushort* __restrict__ Asw, ushort* __restrict__ Qsw,
    float* __restrict__ accum, int* __restrict__ fincount) {
  const int tid = threadIdx.x, g = tid >> 6, l = tid & 63;
  const int n = blockIdx.x * 4 + g;
  if (blockIdx.x == 0 && tid == 0) { accum[0] = 0.f; accum[1] = 0.f; fincount[0] = 0; }

  const float4* xr4 = (const float4*)(x + (size_t)n * SEQ * DD);

  const int d0   = l * 4;
  const int kk   = d0 >> 5, quad = (d0 >> 3) & 3, j = d0 & 7;   // j in {0,4}
  const size_t chunk_d = (size_t)kk * 64 + (size_t)quad * 16;

  float4 a = {0.f, 0.f, 0.f, 0.f};
  #pragma unroll
  for (int s = 0; s < NSUP; ++s) {
    float4 v = xr4[s * 64 + l];
    a.x += v.x; a.y += v.y; a.z += v.z; a.w += v.w;
  }
  a.x *= 0.2f; a.y *= 0.2f; a.z *= 0.2f; a.w *= 0.2f;
  {
    const size_t idx = (((size_t)(n >> 4) * 8) * 64 + chunk_d + (n & 15)) * 8 + j;
    u16x4 o = {f2bf(a.x), f2bf(a.y), f2bf(a.z), f2bf(a.w)};
    *(u16x4*)(Asw + idx) = o;
  }
  float s1 = a.x + a.y + a.z + a.w;
  float s2 = a.x * a.x + a.y * a.y + a.z * a.z + a.w * a.w;
  #pragma unroll
  for (int off = 32; off; off >>= 1) {
    s1 += __shfl_xor(s1, off);
    s2 += __shfl_xor(s2, off);
  }
  if (l == 0) cb[n] = -L2E * (s2 - 2.f * EPS * s1);

  #pragma unroll
  for (int s = 0; s < NQ; ++s) {
    float4 q = xr4[(NSUP + s) * 64 + l];
    const int row = n * NQ + s;
    const size_t idx = (((size_t)(row >> 4) * 8) * 64 + chunk_d + (row & 15)) * 8 + j;
    u16x4 o = {f2bf(q.x), f2bf(q.y), f2bf(q.z), f2bf(q.w)};
    *(u16x4*)(Qsw + idx) = o;
  }
}

// ---------------------------------------------------------------------------
// main r19: r16 (round-4) VERBATIM + exactly ONE change: cb staged to LDS.
// Rationale: in every structure r12-r18, the per-tile GLOBAL load cb[colIdx]
// is issued after the B-prefetch loads and consumed immediately after the
// MFMAs; waiting for the NEWEST VMEM op = s_waitcnt vmcnt(0), which drains
// the entire B-prefetch FIFO every tile (register ping-pong in r12, LDS
// staging in r15-r17). One poison, five structures, one 48-53 us plateau.
// r18 tried to fix this but was confounded: its cE/cO lambda array-refs
// went to scratch (WRITE_SIZE 24 KB -> 4 MB). This round is the clean
// single-variable A/B vs r16: sCb[2048] (8 KB LDS) filled once per block
// (coalesced; covered by the first __syncthreads), per-tile cbv becomes a
// conflict-free broadcast ds_read (quad-replicated lanes -> same address).
// ZERO global loads remain in the main loop.
// Structure (r16): 2 rowg x 8 colg waves, af[2][8] (32 rows/wave), 256-col
// stripe = 16 steps, 2-deep LDS double-buffer, __syncthreads schedule.
// Reduction order identical -> bit-identical output (absmax 0 expected).
// LDS: 128K (Bl) + 8K (sCb) + 6.4K (merge) = 142.4 KB. VGPR ~64: no spill.
// MFMA layouts (verified): A m=lane&15,k=quad*8+j ; B n=lane&15,k=quad*8+j ;
// C col=lane&15,row=quad*4+reg.
// ---------------------------------------------------------------------------
__global__ __launch_bounds__(1024, 4) void proto_main(
    const ushort* __restrict__ Qsw, const ushort* __restrict__ Asw,
    const float* __restrict__ cb, const int* __restrict__ label,
    float* __restrict__ accum, int* __restrict__ fincount,
    float* __restrict__ out) {
  const int tid  = threadIdx.x;
  const int wid  = tid >> 6, lane = tid & 63;
  const int quad = lane >> 4, lcol = lane & 15;
  const int rowg = wid & 1, colg = wid >> 1;        // 2 x 8 wave grid
  const int r0   = blockIdx.x * 64;

  const bf16x8* qb = (const bf16x8*)Qsw;
  const bf16x8* bb = (const bf16x8*)Asw;

  __shared__ bf16x8 Bl[8][2][8][64];                 // 128 KiB B staging
  __shared__ float  sCb[NCOL];                       // 8 KiB col-constant table

  // one-time cb -> LDS (coalesced; ready after the first __syncthreads)
  sCb[tid]        = cb[tid];
  sCb[tid + 1024] = cb[tid + 1024];

  // resident A fragments: this wave's 32 rows (2 sets) x 8 K-chunks (64 VGPR)
  bf16x8 af[2][8];
  #pragma unroll
  for (int set = 0; set < 2; ++set) {
    const size_t base = ((size_t)(blockIdx.x * 4 + rowg * 2 + set) * 8) * 64 + lane;
    #pragma unroll
    for (int kk = 0; kk < 8; ++kk) af[set][kk] = qb[base + (size_t)kk * 64];
  }

  float m[2][4], s[2][4];
  int   bi[2][4];
  #pragma unroll
  for (int set = 0; set < 2; ++set)
    #pragma unroll
    for (int i = 0; i < 4; ++i) {
      m[set][i] = -1e30f; s[set][i] = 0.f; bi[set][i] = 0x7fffffff;
    }

  // wave (rowg) stages K-chunks 4*rowg..4*rowg+3 of tile tl into buf b:
  // 4 x global_load_lds width=16 (linear dest: base + lane*16). [G13/T3]
  const int kk0 = rowg * 4;
  auto stage = [&](int tl, int b) {
    const int T = colg * 16 + tl;
    #pragma unroll
    for (int k2 = 0; k2 < 4; ++k2) {
      const int kk = kk0 + k2;
      const ushort* src = Asw + (((size_t)T * 8 + kk) * 64 + lane) * 8;
      __builtin_amdgcn_global_load_lds(
          (const __attribute__((address_space(1))) void*)src,
          (__attribute__((address_space(3))) void*)&Bl[colg][b][kk][0],
          16, 0, 0);
    }
  };

  auto compute = [&](int tl, int b) {
    f32x4 c0 = {0.f, 0.f, 0.f, 0.f}, c1 = {0.f, 0.f, 0.f, 0.f};
    #pragma unroll
    for (int kk = 0; kk < 8; ++kk) {
      bf16x8 bf = Bl[colg][b][kk][lane];
      c0 = __builtin_amdgcn_mfma_f32_16x16x32_bf16(af[0][kk], bf, c0, 0, 0, 0);
      c1 = __builtin_amdgcn_mfma_f32_16x16x32_bf16(af[1][kk], bf, c1, 0, 0, 0);
    }
    const int   colIdx = (colg * 16 + tl) * 16 + lcol;
    const float cbv    = sCb[colIdx];                // LDS broadcast, no vmcnt
    #pragma unroll
    for (int set = 0; set < 2; ++set) {
      #pragma unroll
      for (int i = 0; i < 4; ++i) {
        float cv = set ? c1[i] : c0[i];
        float v2 = fmaf(cv, 2.f * L2E, cbv);         // log2-frame shifted logit
        float dv = v2 - m[set][i];
        bool  gt = dv > 0.f;
        float e  = exp2f(-fabsf(dv));                // single non-unit exp factor
        s[set][i]  = fmaf(s[set][i], gt ? e : 1.f, gt ? 1.f : e);
        m[set][i]  = fmaxf(m[set][i], v2);
        bi[set][i] = gt ? colIdx : bi[set][i];       // strict >: first max wins
      }
    }
  };

  stage(0, 0);
  __syncthreads();                                   // tile 0 + sCb ready

  #pragma unroll 1
  for (int t = 0; t < 16; t += 2) {
    stage(t + 1, 1);                                 // t+1 always < 16
    compute(t, 0);
    __syncthreads();                                 // t+1 staged; buf0 free
    if (t + 2 < 16) stage(t + 2, 0);
    compute(t + 1, 1);
    __syncthreads();                                 // t+2 staged; buf1 free
  }

  // merge across the 16 lanes sharing rows (cols differ)
  #pragma unroll
  for (int mask = 1; mask < 16; mask <<= 1) {
    #pragma unroll
    for (int set = 0; set < 2; ++set)
      #pragma unroll
      for (int i = 0; i < 4; ++i) {
        float om = __shfl_xor(m[set][i], mask);
        float os = __shfl_xor(s[set][i], mask);
        int   oi = __shfl_xor(bi[set][i], mask);
        float nm = fmaxf(m[set][i], om);
        s[set][i] = s[set][i] * exp2f(m[set][i] - nm) + os * exp2f(om - nm);
        bool better = (om > m[set][i]) || (om == m[set][i] && oi < bi[set][i]);
        bi[set][i] = better ? oi : bi[set][i];
        m[set][i]  = nm;
      }
  }

  __shared__ float sm[8][64], ssh[8][64], slab[64];
  __shared__ int   sbi[8][64];
  if (lcol == 0) {
    #pragma unroll
    for (int set = 0; set < 2; ++set)
      #pragma unroll
      for (int i = 0; i < 4; ++i) {
        int rl = rowg * 32 + set * 16 + quad * 4 + i;
        sm[colg][rl] = m[set][i]; ssh[colg][rl] = s[set][i]; sbi[colg][rl] = bi[set][i];
      }
  }

  // label-logit post-pass (r11-proven): 8 lanes per row, 64 rows -> tids 0..511
  // (whole waves 0..7: shuffles stay wave-uniform); bf16 dot with the same
  // rounding as the MFMA path.
  if (tid < 512) {
    const int rl = tid >> 3, l = tid & 7;
    const int row = r0 + rl;
    const int lab = label[row >> 3];
    const int kk  = l;
    float dot = 0.f;
    const size_t qc = ((size_t)(row >> 4) * 8 + kk) * 64 + (row & 15);
    const size_t ac = ((size_t)(lab >> 4) * 8 + kk) * 64 + (lab & 15);
    #pragma unroll
    for (int qd = 0; qd < 4; ++qd) {
      bf16x8 qv = qb[qc + qd * 16];
      bf16x8 av = bb[ac + qd * 16];
      #pragma unroll
      for (int j = 0; j < 8; ++j) dot = fmaf(bf2f(qv[j]), bf2f(av[j]), dot);
    }
    dot += __shfl_xor(dot, 1);
    dot += __shfl_xor(dot, 2);
    dot += __shfl_xor(dot, 4);
    if (l == 0) slab[rl] = fmaf(dot, 2.f * L2E, sCb[lab]);  // shifted label logit
  }
  __syncthreads();

  if (tid < 64) {                                  // one full wave
    float mm = sm[0][tid], sv = ssh[0][tid];
    int   b  = sbi[0][tid];
    #pragma unroll
    for (int w = 1; w < 8; ++w) {                  // stripes in ascending col order
      float om = sm[w][tid], os = ssh[w][tid];
      int   oi = sbi[w][tid];
      float nm = fmaxf(mm, om);
      sv = sv * exp2f(mm - nm) + os * exp2f(om - nm);
      bool better = (om > mm) || (om == mm && oi < b);
      b = better ? oi : b;
      mm = nm;
    }
    const int row = r0 + tid;
    const int lb  = label[row >> 3];
    float loss = LN2 * (mm + log2f(sv) - slab[tid]);
    float corr = (b == lb) ? 1.f : 0.f;
    #pragma unroll
    for (int mask = 32; mask; mask >>= 1) {        // full-wave xor reduce
      loss += __shfl_xor(loss, mask);
      corr += __shfl_xor(corr, mask);
    }
    if (tid == 0) {
      atomicAdd(&accum[0], loss);
      atomicAdd(&accum[1], corr);
      __threadfence();
      if (atomicAdd(fincount, 1) == (int)gridDim.x - 1) {
        out[0] = atomicAdd(&accum[0], 0.f) / (float)NROW;   // coherent reads
        out[1] = atomicAdd(&accum[1], 0.f) * 100.f / (float)NROW;
      }
    }
  }
}

// ---------------------------------------------------------------------------
extern "C" void kernel_launch(void* const* d_in, const int* in_sizes, int n_in,
                              void* d_out, int out_size, void* d_ws, size_t ws_size,
                              hipStream_t stream) {
  const float* x     = (const float*)d_in[0];
  const int*   label = (const int*)d_in[1];
  float* out = (float*)d_out;

  // ws layout (float-sized slots): [0:2) accum | [2] fincount |
  // [16,16+NCOL) cb | Asw (NCOL*DD ushort) | Qsw (NROW*DD ushort)
  float*  W        = (float*)d_ws;
  float*  accum    = W;
  int*    fincount = (int*)(W + 2);
  float*  cb       = W + 16;
  ushort* Asw      = (ushort*)(cb + NCOL);
  ushort* Qsw      = Asw + (size_t)NCOL * DD;

  hipLaunchKernelGGL(proto_prep, dim3(NEP / 4), dim3(256), 0, stream,
                     x, cb, Asw, Qsw, accum, fincount);
  hipLaunchKernelGGL(proto_main, dim3(NROW / 64), dim3(1024), 0, stream,
                     Qsw, Asw, cb, label, accum, fincount, out);
}

// Round 8
// 121.081 us; speedup vs baseline: 1.0716x; 1.0055x over previous
//
#include <hip/hip_runtime.h>
#include <math.h>

#define EPS  1e-6f
#define DD   256
#define NSUP 5
#define NQ   8
#define SEQ  13
#define L2E  1.44269504088896f
#define LN2  0.693147180559945f
#define NEP  2048            // episodes
#define NROW 16384           // NEP*NQ query rows
#define NCOL 2048            // anchor columns

typedef short bf16x8 __attribute__((ext_vector_type(8)));
typedef unsigned short u16x4 __attribute__((ext_vector_type(4)));
typedef float f32x4  __attribute__((ext_vector_type(4)));

__device__ __forceinline__ ushort f2bf(float f) {
  union { float f; unsigned u; } v; v.f = f;
  unsigned r = v.u + 0x7FFFu + ((v.u >> 16) & 1u);   // round-to-nearest-even
  return (ushort)(r >> 16);
}
__device__ __forceinline__ float bf2f(short u) {
  union { unsigned u; float f; } v; v.u = ((unsigned)(unsigned short)u) << 16;
  return v.f;
}

// ---------------------------------------------------------------------------
// prep (r8-proven, unchanged): anchors/queries in MFMA-fragment-SWIZZLED order;
// element (c,d) -> ushort idx (((c>>4)*8+(d>>5))*64 + ((d>>3)&3)*16 + (c&15))*8+(d&7).
// cb[c] = -log2(e)*(sum(a^2) - 2*eps*sum(a)); row-constant cq cancels.
// ---------------------------------------------------------------------------
__global__ __launch_bounds__(256) void proto_prep(
    const float* __restrict__ x, float* __restrict__ cb,
    ushort* __restrict__ Asw, ushort* __restrict__ Qsw,
    float* __restrict__ accum, int* __restrict__ fincount) {
  const int tid = threadIdx.x, g = tid >> 6, l = tid & 63;
  const int n = blockIdx.x * 4 + g;
  if (blockIdx.x == 0 && tid == 0) { accum[0] = 0.f; accum[1] = 0.f; fincount[0] = 0; }

  const float4* xr4 = (const float4*)(x + (size_t)n * SEQ * DD);

  const int d0   = l * 4;
  const int kk   = d0 >> 5, quad = (d0 >> 3) & 3, j = d0 & 7;   // j in {0,4}
  const size_t chunk_d = (size_t)kk * 64 + (size_t)quad * 16;

  float4 a = {0.f, 0.f, 0.f, 0.f};
  #pragma unroll
  for (int s = 0; s < NSUP; ++s) {
    float4 v = xr4[s * 64 + l];
    a.x += v.x; a.y += v.y; a.z += v.z; a.w += v.w;
  }
  a.x *= 0.2f; a.y *= 0.2f; a.z *= 0.2f; a.w *= 0.2f;
  {
    const size_t idx = (((size_t)(n >> 4) * 8) * 64 + chunk_d + (n & 15)) * 8 + j;
    u16x4 o = {f2bf(a.x), f2bf(a.y), f2bf(a.z), f2bf(a.w)};
    *(u16x4*)(Asw + idx) = o;
  }
  float s1 = a.x + a.y + a.z + a.w;
  float s2 = a.x * a.x + a.y * a.y + a.z * a.z + a.w * a.w;
  #pragma unroll
  for (int off = 32; off; off >>= 1) {
    s1 += __shfl_xor(s1, off);
    s2 += __shfl_xor(s2, off);
  }
  if (l == 0) cb[n] = -L2E * (s2 - 2.f * EPS * s1);

  #pragma unroll
  for (int s = 0; s < NQ; ++s) {
    float4 q = xr4[(NSUP + s) * 64 + l];
    const int row = n * NQ + s;
    const size_t idx = (((size_t)(row >> 4) * 8) * 64 + chunk_d + (row & 15)) * 8 + j;
    u16x4 o = {f2bf(q.x), f2bf(q.y), f2bf(q.z), f2bf(q.w)};
    *(u16x4*)(Qsw + idx) = o;
  }
}

// ---------------------------------------------------------------------------
// main r20: CROSS-BLOCK DECORRELATION. r12-r19 falsified every CU-local wall
// (occupancy, spill, LDS volume, step count, barrier drain, counted vmcnt,
// in-loop global loads): five structures, one 48-53 us plateau with ~50%
// issue-idle and a ~60k-cycle latency component no CU-local model produces.
// The untouched invariant: all 256 blocks run the SAME tile schedule in
// near-lockstep -> the 32 CUs per XCD request the SAME B addresses from
// their shared L2 simultaneously; same-address streams serialize on L2
// banks (no broadcast), turning ~300-cyc L2 latency into multi-thousand-
// cycle effective latency (matches r12's 3960 cyc/tile vs ~460 issue).
// Fix: block bx processes each stripe's tiles in rotated order (t+bx)&15 ->
// blocks spread over 16 phase offsets (~2 CUs/XCD per tile-phase, was 32).
// Numerics: m is order-independent; argmax hardened to explicit lowest-
// index-wins (dv==0 && colIdx<bi clause; identical semantics unrotated,
// order-independent rotated); s accumulation order changes -> ~ulp-level
// fp difference expected (absmax ~1e-6, was 0.0).
// Structure otherwise r19 verbatim: 2 rowg x 8 colg, af[2][8], 16 steps,
// 2-deep LDS dbuf, sCb in LDS, __syncthreads schedule.
// MFMA layouts (verified): A m=lane&15,k=quad*8+j ; B n=lane&15,k=quad*8+j ;
// C col=lane&15,row=quad*4+reg.
// ---------------------------------------------------------------------------
__global__ __launch_bounds__(1024, 4) void proto_main(
    const ushort* __restrict__ Qsw, const ushort* __restrict__ Asw,
    const float* __restrict__ cb, const int* __restrict__ label,
    float* __restrict__ accum, int* __restrict__ fincount,
    float* __restrict__ out) {
  const int tid  = threadIdx.x;
  const int wid  = tid >> 6, lane = tid & 63;
  const int quad = lane >> 4, lcol = lane & 15;
  const int rowg = wid & 1, colg = wid >> 1;        // 2 x 8 wave grid
  const int r0   = blockIdx.x * 64;
  const int rot  = blockIdx.x & 15;                 // per-block tile phase

  const bf16x8* qb = (const bf16x8*)Qsw;
  const bf16x8* bb = (const bf16x8*)Asw;

  __shared__ bf16x8 Bl[8][2][8][64];                 // 128 KiB B staging
  __shared__ float  sCb[NCOL];                       // 8 KiB col-constant table

  // one-time cb -> LDS (coalesced; ready after the first __syncthreads)
  sCb[tid]        = cb[tid];
  sCb[tid + 1024] = cb[tid + 1024];

  // resident A fragments: this wave's 32 rows (2 sets) x 8 K-chunks (64 VGPR)
  bf16x8 af[2][8];
  #pragma unroll
  for (int set = 0; set < 2; ++set) {
    const size_t base = ((size_t)(blockIdx.x * 4 + rowg * 2 + set) * 8) * 64 + lane;
    #pragma unroll
    for (int kk = 0; kk < 8; ++kk) af[set][kk] = qb[base + (size_t)kk * 64];
  }

  float m[2][4], s[2][4];
  int   bi[2][4];
  #pragma unroll
  for (int set = 0; set < 2; ++set)
    #pragma unroll
    for (int i = 0; i < 4; ++i) {
      m[set][i] = -1e30f; s[set][i] = 0.f; bi[set][i] = 0x7fffffff;
    }

  // wave (rowg) stages K-chunks 4*rowg..4*rowg+3 of (rotated) tile tl into
  // buf b: 4 x global_load_lds width=16 (linear dest: base + lane*16).
  const int kk0 = rowg * 4;
  auto stage = [&](int tl, int b) {
    const int T = colg * 16 + ((tl + rot) & 15);     // rotated tile index
    #pragma unroll
    for (int k2 = 0; k2 < 4; ++k2) {
      const int kk = kk0 + k2;
      const ushort* src = Asw + (((size_t)T * 8 + kk) * 64 + lane) * 8;
      __builtin_amdgcn_global_load_lds(
          (const __attribute__((address_space(1))) void*)src,
          (__attribute__((address_space(3))) void*)&Bl[colg][b][kk][0],
          16, 0, 0);
    }
  };

  auto compute = [&](int tl, int b) {
    f32x4 c0 = {0.f, 0.f, 0.f, 0.f}, c1 = {0.f, 0.f, 0.f, 0.f};
    #pragma unroll
    for (int kk = 0; kk < 8; ++kk) {
      bf16x8 bf = Bl[colg][b][kk][lane];
      c0 = __builtin_amdgcn_mfma_f32_16x16x32_bf16(af[0][kk], bf, c0, 0, 0, 0);
      c1 = __builtin_amdgcn_mfma_f32_16x16x32_bf16(af[1][kk], bf, c1, 0, 0, 0);
    }
    const int   colIdx = (colg * 16 + ((tl + rot) & 15)) * 16 + lcol;
    const float cbv    = sCb[colIdx];                // LDS broadcast, no vmcnt
    #pragma unroll
    for (int set = 0; set < 2; ++set) {
      #pragma unroll
      for (int i = 0; i < 4; ++i) {
        float cv = set ? c1[i] : c0[i];
        float v2 = fmaf(cv, 2.f * L2E, cbv);         // log2-frame shifted logit
        float dv = v2 - m[set][i];
        bool  gt = dv > 0.f;
        float e  = exp2f(-fabsf(dv));                // single non-unit exp factor
        // lowest-index-wins argmax, order-independent (ties: dv==0)
        bool  bb2 = gt || (dv == 0.f && colIdx < bi[set][i]);
        s[set][i]  = fmaf(s[set][i], gt ? e : 1.f, gt ? 1.f : e);
        m[set][i]  = fmaxf(m[set][i], v2);
        bi[set][i] = bb2 ? colIdx : bi[set][i];
      }
    }
  };

  stage(0, 0);
  __syncthreads();                                   // tile 0 + sCb ready

  #pragma unroll 1
  for (int t = 0; t < 16; t += 2) {
    stage(t + 1, 1);                                 // t+1 always < 16
    compute(t, 0);
    __syncthreads();                                 // t+1 staged; buf0 free
    if (t + 2 < 16) stage(t + 2, 0);
    compute(t + 1, 1);
    __syncthreads();                                 // t+2 staged; buf1 free
  }

  // merge across the 16 lanes sharing rows (cols differ)
  #pragma unroll
  for (int mask = 1; mask < 16; mask <<= 1) {
    #pragma unroll
    for (int set = 0; set < 2; ++set)
      #pragma unroll
      for (int i = 0; i < 4; ++i) {
        float om = __shfl_xor(m[set][i], mask);
        float os = __shfl_xor(s[set][i], mask);
        int   oi = __shfl_xor(bi[set][i], mask);
        float nm = fmaxf(m[set][i], om);
        s[set][i] = s[set][i] * exp2f(m[set][i] - nm) + os * exp2f(om - nm);
        bool better = (om > m[set][i]) || (om == m[set][i] && oi < bi[set][i]);
        bi[set][i] = better ? oi : bi[set][i];
        m[set][i]  = nm;
      }
  }

  __shared__ float sm[8][64], ssh[8][64], slab[64];
  __shared__ int   sbi[8][64];
  if (lcol == 0) {
    #pragma unroll
    for (int set = 0; set < 2; ++set)
      #pragma unroll
      for (int i = 0; i < 4; ++i) {
        int rl = rowg * 32 + set * 16 + quad * 4 + i;
        sm[colg][rl] = m[set][i]; ssh[colg][rl] = s[set][i]; sbi[colg][rl] = bi[set][i];
      }
  }

  // label-logit post-pass (r11-proven): 8 lanes per row, 64 rows -> tids 0..511
  // (whole waves 0..7: shuffles stay wave-uniform); bf16 dot with the same
  // rounding as the MFMA path.
  if (tid < 512) {
    const int rl = tid >> 3, l = tid & 7;
    const int row = r0 + rl;
    const int lab = label[row >> 3];
    const int kk  = l;
    float dot = 0.f;
    const size_t qc = ((size_t)(row >> 4) * 8 + kk) * 64 + (row & 15);
    const size_t ac = ((size_t)(lab >> 4) * 8 + kk) * 64 + (lab & 15);
    #pragma unroll
    for (int qd = 0; qd < 4; ++qd) {
      bf16x8 qv = qb[qc + qd * 16];
      bf16x8 av = bb[ac + qd * 16];
      #pragma unroll
      for (int j = 0; j < 8; ++j) dot = fmaf(bf2f(qv[j]), bf2f(av[j]), dot);
    }
    dot += __shfl_xor(dot, 1);
    dot += __shfl_xor(dot, 2);
    dot += __shfl_xor(dot, 4);
    if (l == 0) slab[rl] = fmaf(dot, 2.f * L2E, sCb[lab]);  // shifted label logit
  }
  __syncthreads();

  if (tid < 64) {                                  // one full wave
    float mm = sm[0][tid], sv = ssh[0][tid];
    int   b  = sbi[0][tid];
    #pragma unroll
    for (int w = 1; w < 8; ++w) {                  // stripes in ascending col order
      float om = sm[w][tid], os = ssh[w][tid];
      int   oi = sbi[w][tid];
      float nm = fmaxf(mm, om);
      sv = sv * exp2f(mm - nm) + os * exp2f(om - nm);
      bool better = (om > mm) || (om == mm && oi < b);
      b = better ? oi : b;
      mm = nm;
    }
    const int row = r0 + tid;
    const int lb  = label[row >> 3];
    float loss = LN2 * (mm + log2f(sv) - slab[tid]);
    float corr = (b == lb) ? 1.f : 0.f;
    #pragma unroll
    for (int mask = 32; mask; mask >>= 1) {        // full-wave xor reduce
      loss += __shfl_xor(loss, mask);
      corr += __shfl_xor(corr, mask);
    }
    if (tid == 0) {
      atomicAdd(&accum[0], loss);
      atomicAdd(&accum[1], corr);
      __threadfence();
      if (atomicAdd(fincount, 1) == (int)gridDim.x - 1) {
        out[0] = atomicAdd(&accum[0], 0.f) / (float)NROW;   // coherent reads
        out[1] = atomicAdd(&accum[1], 0.f) * 100.f / (float)NROW;
      }
    }
  }
}

// ---------------------------------------------------------------------------
extern "C" void kernel_launch(void* const* d_in, const int* in_sizes, int n_in,
                              void* d_out, int out_size, void* d_ws, size_t ws_size,
                              hipStream_t stream) {
  const float* x     = (const float*)d_in[0];
  const int*   label = (const int*)d_in[1];
  float* out = (float*)d_out;

  // ws layout (float-sized slots): [0:2) accum | [2] fincount |
  // [16,16+NCOL) cb | Asw (NCOL*DD ushort) | Qsw (NROW*DD ushort)
  float*  W        = (float*)d_ws;
  float*  accum    = W;
  int*    fincount = (int*)(W + 2);
  float*  cb       = W + 16;
  ushort* Asw      = (ushort*)(cb + NCOL);
  ushort* Qsw      = Asw + (size_t)NCOL * DD;

  hipLaunchKernelGGL(proto_prep, dim3(NEP / 4), dim3(256), 0, stream,
                     x, cb, Asw, Qsw, accum, fincount);
  hipLaunchKernelGGL(proto_main, dim3(NROW / 64), dim3(1024), 0, stream,
                     Qsw, Asw, cb, label, accum, fincount, out);
}

// Round 9
// 119.029 us; speedup vs baseline: 1.0901x; 1.0172x over previous
//
#include <hip/hip_runtime.h>
#include <math.h>

#define EPS  1e-6f
#define DD   256
#define NSUP 5
#define NQ   8
#define SEQ  13
#define L2E  1.44269504088896f
#define LN2  0.693147180559945f
#define NEP  2048            // episodes
#define NROW 16384           // NEP*NQ query rows
#define NCOL 2048            // anchor columns

typedef short bf16x8 __attribute__((ext_vector_type(8)));
typedef unsigned short u16x4 __attribute__((ext_vector_type(4)));
typedef float f32x4  __attribute__((ext_vector_type(4)));

__device__ __forceinline__ ushort f2bf(float f) {
  union { float f; unsigned u; } v; v.f = f;
  unsigned r = v.u + 0x7FFFu + ((v.u >> 16) & 1u);   // round-to-nearest-even
  return (ushort)(r >> 16);
}
__device__ __forceinline__ float bf2f(short u) {
  union { unsigned u; float f; } v; v.u = ((unsigned)(unsigned short)u) << 16;
  return v.f;
}

// ---------------------------------------------------------------------------
// prep (r8-proven, unchanged): anchors/queries in MFMA-fragment-SWIZZLED order;
// element (c,d) -> ushort idx (((c>>4)*8+(d>>5))*64 + ((d>>3)&3)*16 + (c&15))*8+(d&7).
// cb[c] = -log2(e)*(sum(a^2) - 2*eps*sum(a)); row-constant cq cancels.
// ---------------------------------------------------------------------------
__global__ __launch_bounds__(256) void proto_prep(
    const float* __restrict__ x, float* __restrict__ cb,
    ushort* __restrict__ Asw, ushort* __restrict__ Qsw,
    float* __restrict__ accum, int* __restrict__ fincount) {
  const int tid = threadIdx.x, g = tid >> 6, l = tid & 63;
  const int n = blockIdx.x * 4 + g;
  if (blockIdx.x == 0 && tid == 0) { accum[0] = 0.f; accum[1] = 0.f; fincount[0] = 0; }

  const float4* xr4 = (const float4*)(x + (size_t)n * SEQ * DD);

  const int d0   = l * 4;
  const int kk   = d0 >> 5, quad = (d0 >> 3) & 3, j = d0 & 7;   // j in {0,4}
  const size_t chunk_d = (size_t)kk * 64 + (size_t)quad * 16;

  float4 a = {0.f, 0.f, 0.f, 0.f};
  #pragma unroll
  for (int s = 0; s < NSUP; ++s) {
    float4 v = xr4[s * 64 + l];
    a.x += v.x; a.y += v.y; a.z += v.z; a.w += v.w;
  }
  a.x *= 0.2f; a.y *= 0.2f; a.z *= 0.2f; a.w *= 0.2f;
  {
    const size_t idx = (((size_t)(n >> 4) * 8) * 64 + chunk_d + (n & 15)) * 8 + j;
    u16x4 o = {f2bf(a.x), f2bf(a.y), f2bf(a.z), f2bf(a.w)};
    *(u16x4*)(Asw + idx) = o;
  }
  float s1 = a.x + a.y + a.z + a.w;
  float s2 = a.x * a.x + a.y * a.y + a.z * a.z + a.w * a.w;
  #pragma unroll
  for (int off = 32; off; off >>= 1) {
    s1 += __shfl_xor(s1, off);
    s2 += __shfl_xor(s2, off);
  }
  if (l == 0) cb[n] = -L2E * (s2 - 2.f * EPS * s1);

  #pragma unroll
  for (int s = 0; s < NQ; ++s) {
    float4 q = xr4[(NSUP + s) * 64 + l];
    const int row = n * NQ + s;
    const size_t idx = (((size_t)(row >> 4) * 8) * 64 + chunk_d + (row & 15)) * 8 + j;
    u16x4 o = {f2bf(q.x), f2bf(q.y), f2bf(q.z), f2bf(q.w)};
    *(u16x4*)(Qsw + idx) = o;
  }
}

// ---------------------------------------------------------------------------
// main r21: B-FLOW HALVING test (the last invariant). Across r12-r20, every
// kernel made each CU consume exactly 1 MB of B from L2 (64rows x 2048cols
// decomposition) and every kernel took ~50 us = 20 GB/s/CU, while occupancy,
// spill, LDS, barriers, vmcnt, VALU load, cross-block phase were all varied
// and falsified. This round: block = 128 rows x 1024 cols (grid 256 = 128
// row-blocks x 2 col-chunks) -> per-CU B = 512 KB (HALVED); per-SIMD MFMA
// unchanged (1024); the wave inner loop is byte-identical to r19 (af[2][8],
// 16 steps, 2-deep dbuf, sCb broadcast). 16 waves = 4 rowg x 4 colg.
// Rows span 2 blocks -> per-(row,chunk) partials {m,s,bi} + slab (colc==0)
// written to workspace; proto_merge (16384 threads) does the 2-way chunk
// merge + loss/prec and finalizes. Within-stripe + stripe-merge order
// unchanged; only the final chunk merge changes s association -> absmax
// ~1e-7 expected (argmax exact via lowest-index-wins).
// LDS: Bl 64K + sCb 4K + merge 10K = 78 KB. VGPR ~64: no spill.
// MFMA layouts (verified): A m=lane&15,k=quad*8+j ; B n=lane&15,k=quad*8+j ;
// C col=lane&15,row=quad*4+reg.
// ---------------------------------------------------------------------------
__global__ __launch_bounds__(1024, 4) void proto_main(
    const ushort* __restrict__ Qsw, const ushort* __restrict__ Asw,
    const float* __restrict__ cb, const int* __restrict__ label,
    float* __restrict__ partm, float* __restrict__ parts,
    int* __restrict__ partbi, float* __restrict__ slabws) {
  const int tid  = threadIdx.x;
  const int wid  = tid >> 6, lane = tid & 63;
  const int quad = lane >> 4, lcol = lane & 15;
  const int rowg = wid & 3, colg = wid >> 2;        // 4 x 4 wave grid
  const int rb   = blockIdx.x >> 1;                 // row-block (128 rows)
  const int colc = blockIdx.x & 1;                  // col-chunk (1024 cols)
  const int r0   = rb * 128;

  const bf16x8* qb = (const bf16x8*)Qsw;
  const bf16x8* bb = (const bf16x8*)Asw;

  __shared__ bf16x8 Bl[4][2][8][64];                 // 64 KiB B staging
  __shared__ float  sCb[1024];                       // this chunk's col consts

  sCb[tid] = cb[colc * 1024 + tid];                  // one-time, coalesced

  // resident A fragments: this wave's 32 rows (2 sets) x 8 K-chunks (64 VGPR)
  bf16x8 af[2][8];
  #pragma unroll
  for (int set = 0; set < 2; ++set) {
    const size_t base = ((size_t)(rb * 8 + rowg * 2 + set) * 8) * 64 + lane;
    #pragma unroll
    for (int kk = 0; kk < 8; ++kk) af[set][kk] = qb[base + (size_t)kk * 64];
  }

  float m[2][4], s[2][4];
  int   bi[2][4];
  #pragma unroll
  for (int set = 0; set < 2; ++set)
    #pragma unroll
    for (int i = 0; i < 4; ++i) {
      m[set][i] = -1e30f; s[set][i] = 0.f; bi[set][i] = 0x7fffffff;
    }

  // wave (rowg) stages K-chunks {2*rowg, 2*rowg+1} of tile tl into buf b:
  // 2 x global_load_lds width=16 (linear dest: base + lane*16). [G13/T3]
  const int kk0 = rowg * 2;
  auto stage = [&](int tl, int b) {
    const int T = colc * 64 + colg * 16 + tl;        // global 16-col tile id
    #pragma unroll
    for (int k2 = 0; k2 < 2; ++k2) {
      const int kk = kk0 + k2;
      const ushort* src = Asw + (((size_t)T * 8 + kk) * 64 + lane) * 8;
      __builtin_amdgcn_global_load_lds(
          (const __attribute__((address_space(1))) void*)src,
          (__attribute__((address_space(3))) void*)&Bl[colg][b][kk][0],
          16, 0, 0);
    }
  };

  auto compute = [&](int tl, int b) {
    f32x4 c0 = {0.f, 0.f, 0.f, 0.f}, c1 = {0.f, 0.f, 0.f, 0.f};
    #pragma unroll
    for (int kk = 0; kk < 8; ++kk) {
      bf16x8 bf = Bl[colg][b][kk][lane];
      c0 = __builtin_amdgcn_mfma_f32_16x16x32_bf16(af[0][kk], bf, c0, 0, 0, 0);
      c1 = __builtin_amdgcn_mfma_f32_16x16x32_bf16(af[1][kk], bf, c1, 0, 0, 0);
    }
    const int   lcIdx  = (colg * 16 + tl) * 16 + lcol;   // chunk-local col
    const int   colIdx = colc * 1024 + lcIdx;            // global col (for bi)
    const float cbv    = sCb[lcIdx];                     // LDS broadcast
    #pragma unroll
    for (int set = 0; set < 2; ++set) {
      #pragma unroll
      for (int i = 0; i < 4; ++i) {
        float cv = set ? c1[i] : c0[i];
        float v2 = fmaf(cv, 2.f * L2E, cbv);         // log2-frame shifted logit
        float dv = v2 - m[set][i];
        bool  gt = dv > 0.f;
        float e  = exp2f(-fabsf(dv));                // single non-unit exp factor
        s[set][i]  = fmaf(s[set][i], gt ? e : 1.f, gt ? 1.f : e);
        m[set][i]  = fmaxf(m[set][i], v2);
        bi[set][i] = gt ? colIdx : bi[set][i];       // strict >: first max wins
      }
    }
  };

  stage(0, 0);
  __syncthreads();                                   // tile 0 + sCb ready

  #pragma unroll 1
  for (int t = 0; t < 16; t += 2) {
    stage(t + 1, 1);                                 // t+1 always < 16
    compute(t, 0);
    __syncthreads();                                 // t+1 staged; buf0 free
    if (t + 2 < 16) stage(t + 2, 0);
    compute(t + 1, 1);
    __syncthreads();                                 // t+2 staged; buf1 free
  }

  // merge across the 16 lanes sharing rows (cols differ)
  #pragma unroll
  for (int mask = 1; mask < 16; mask <<= 1) {
    #pragma unroll
    for (int set = 0; set < 2; ++set)
      #pragma unroll
      for (int i = 0; i < 4; ++i) {
        float om = __shfl_xor(m[set][i], mask);
        float os = __shfl_xor(s[set][i], mask);
        int   oi = __shfl_xor(bi[set][i], mask);
        float nm = fmaxf(m[set][i], om);
        s[set][i] = s[set][i] * exp2f(m[set][i] - nm) + os * exp2f(om - nm);
        bool better = (om > m[set][i]) || (om == m[set][i] && oi < bi[set][i]);
        bi[set][i] = better ? oi : bi[set][i];
        m[set][i]  = nm;
      }
  }

  __shared__ float sm[4][128], ssh[4][128];
  __shared__ int   sbi[4][128];
  if (lcol == 0) {
    #pragma unroll
    for (int set = 0; set < 2; ++set)
      #pragma unroll
      for (int i = 0; i < 4; ++i) {
        int rl = rowg * 32 + set * 16 + quad * 4 + i;
        sm[colg][rl] = m[set][i]; ssh[colg][rl] = s[set][i]; sbi[colg][rl] = bi[set][i];
      }
  }
  __syncthreads();

  // in-block merge over the 4 colg stripes (ascending cols) -> ws partials
  if (tid < 128) {
    float mm = sm[0][tid], sv = ssh[0][tid];
    int   b  = sbi[0][tid];
    #pragma unroll
    for (int w = 1; w < 4; ++w) {
      float om = sm[w][tid], os = ssh[w][tid];
      int   oi = sbi[w][tid];
      float nm = fmaxf(mm, om);
      sv = sv * exp2f(mm - nm) + os * exp2f(om - nm);
      bool better = (om > mm) || (om == mm && oi < b);
      b = better ? oi : b;
      mm = nm;
    }
    const int row = r0 + tid;
    partm [colc * NROW + row] = mm;
    parts [colc * NROW + row] = sv;
    partbi[colc * NROW + row] = b;
  }

  // label-logit pass (r11-proven), colc==0 blocks only: 8 lanes/row x 128
  // rows = 1024 threads; bf16 dot with the same rounding as the MFMA path.
  if (colc == 0) {
    const int rl = tid >> 3, l = tid & 7;
    const int row = r0 + rl;
    const int lab = label[row >> 3];
    const int kk  = l;
    float dot = 0.f;
    const size_t qc = ((size_t)(row >> 4) * 8 + kk) * 64 + (row & 15);
    const size_t ac = ((size_t)(lab >> 4) * 8 + kk) * 64 + (lab & 15);
    #pragma unroll
    for (int qd = 0; qd < 4; ++qd) {
      bf16x8 qv = qb[qc + qd * 16];
      bf16x8 av = bb[ac + qd * 16];
      #pragma unroll
      for (int j = 0; j < 8; ++j) dot = fmaf(bf2f(qv[j]), bf2f(av[j]), dot);
    }
    dot += __shfl_xor(dot, 1);
    dot += __shfl_xor(dot, 2);
    dot += __shfl_xor(dot, 4);
    if (l == 0) slabws[row] = fmaf(dot, 2.f * L2E, cb[lab]);
  }
}

// ---------------------------------------------------------------------------
// merge: 16384 rows, one thread each; 2-way chunk merge + loss/prec1 finalize.
// ---------------------------------------------------------------------------
__global__ __launch_bounds__(256) void proto_merge(
    const float* __restrict__ partm, const float* __restrict__ parts,
    const int* __restrict__ partbi, const float* __restrict__ slabws,
    const int* __restrict__ label,
    float* __restrict__ accum, int* __restrict__ fincount,
    float* __restrict__ out) {
  const int tid = threadIdx.x, row = blockIdx.x * 256 + tid;
  const int wid = tid >> 6;

  float m0 = partm[row],  m1 = partm[NROW + row];
  float s0 = parts[row],  s1 = parts[NROW + row];
  int   b0 = partbi[row], b1 = partbi[NROW + row];
  float nm = fmaxf(m0, m1);
  float sv = s0 * exp2f(m0 - nm) + s1 * exp2f(m1 - nm);
  bool better = (m1 > m0) || (m1 == m0 && b1 < b0);
  int  b  = better ? b1 : b0;

  const int lb = label[row >> 3];
  float loss = LN2 * (nm + log2f(sv) - slabws[row]);
  float corr = (b == lb) ? 1.f : 0.f;

  #pragma unroll
  for (int mask = 32; mask; mask >>= 1) {
    loss += __shfl_xor(loss, mask);
    corr += __shfl_xor(corr, mask);
  }
  __shared__ float red[2][4];
  if ((tid & 63) == 0) { red[0][wid] = loss; red[1][wid] = corr; }
  __syncthreads();
  if (tid == 0) {
    float L = red[0][0] + red[0][1] + red[0][2] + red[0][3];
    float C = red[1][0] + red[1][1] + red[1][2] + red[1][3];
    atomicAdd(&accum[0], L);
    atomicAdd(&accum[1], C);
    __threadfence();
    if (atomicAdd(fincount, 1) == (int)gridDim.x - 1) {
      out[0] = atomicAdd(&accum[0], 0.f) / (float)NROW;     // coherent reads
      out[1] = atomicAdd(&accum[1], 0.f) * 100.f / (float)NROW;
    }
  }
}

// ---------------------------------------------------------------------------
extern "C" void kernel_launch(void* const* d_in, const int* in_sizes, int n_in,
                              void* d_out, int out_size, void* d_ws, size_t ws_size,
                              hipStream_t stream) {
  const float* x     = (const float*)d_in[0];
  const int*   label = (const int*)d_in[1];
  float* out = (float*)d_out;

  // ws layout (float-sized slots): [0:2) accum | [2] fincount |
  // [16,16+NCOL) cb | Asw (NCOL*DD ushort) | Qsw (NROW*DD ushort) |
  // partm[2*NROW] | parts[2*NROW] | partbi[2*NROW] | slab[NROW]  (~450 KB)
  float*  W        = (float*)d_ws;
  float*  accum    = W;
  int*    fincount = (int*)(W + 2);
  float*  cb       = W + 16;
  ushort* Asw      = (ushort*)(cb + NCOL);
  ushort* Qsw      = Asw + (size_t)NCOL * DD;
  float*  partm    = (float*)(Qsw + (size_t)NROW * DD);
  float*  parts    = partm + 2 * NROW;
  int*    partbi   = (int*)(parts + 2 * NROW);
  float*  slabws   = (float*)(partbi + 2 * NROW);

  hipLaunchKernelGGL(proto_prep, dim3(NEP / 4), dim3(256), 0, stream,
                     x, cb, Asw, Qsw, accum, fincount);
  hipLaunchKernelGGL(proto_main, dim3(256), dim3(1024), 0, stream,
                     Qsw, Asw, cb, label, partm, parts, partbi, slabws);
  hipLaunchKernelGGL(proto_merge, dim3(NROW / 256), dim3(256), 0, stream,
                     partm, parts, partbi, slabws, label, accum, fincount, out);
}